// Round 1
// baseline (525.842 us; speedup 1.0000x reference)
//
#include <hip/hip_runtime.h>
#include <hip/hip_bf16.h>

typedef float f32x2 __attribute__((ext_vector_type(2)));

#define HEADS 8
#define OUT_DIM 8
#define HID 64
#define IN_NODE 128
#define IN_EDGE 64

// ---------------------------------------------------------------------------
// QKV projection: out[node][j] = sum_k h[node][k] * W[k][j] + b[j]
// grid = (chunks, 3): blockIdx.y selects {Q,K,V}. block = 64 (one wave).
// Lane j holds W column j as float2 pairs (128 VGPRs), reused across nodes.
// h row read via wave-uniform float4 loads (broadcast / scalarizable).
// ---------------------------------------------------------------------------
__global__ __launch_bounds__(64) void qkv_kernel(
    const float* __restrict__ h,
    const float* __restrict__ WQ, const float* __restrict__ bQ,
    const float* __restrict__ WK, const float* __restrict__ bK,
    const float* __restrict__ WV, const float* __restrict__ bV,
    float* __restrict__ Q, float* __restrict__ K, float* __restrict__ V,
    int n_nodes, int npb)
{
    const int lane = threadIdx.x;
    const int mat = blockIdx.y;
    const float* __restrict__ W  = (mat == 0) ? WQ : (mat == 1) ? WK : WV;
    const float* __restrict__ bp = (mat == 0) ? bQ : (mat == 1) ? bK : bV;
    float* __restrict__ out      = (mat == 0) ? Q  : (mat == 1) ? K  : V;

    f32x2 wc2[IN_NODE / 2];
#pragma unroll
    for (int t = 0; t < IN_NODE / 2; ++t) {
        wc2[t].x = W[(2 * t) * HID + lane];
        wc2[t].y = W[(2 * t + 1) * HID + lane];
    }
    const float bias = bp[lane];

    int n0 = blockIdx.x * npb;
    int n1 = n0 + npb; if (n1 > n_nodes) n1 = n_nodes;
    for (int node = n0; node < n1; ++node) {
        const float* __restrict__ hrow = h + (size_t)node * IN_NODE;
        f32x2 acc2 = {bias, 0.0f};
#pragma unroll
        for (int kk = 0; kk < IN_NODE; kk += 4) {
            float4 hv = *reinterpret_cast<const float4*>(hrow + kk);
            f32x2 a = {hv.x, hv.y};
            f32x2 b = {hv.z, hv.w};
            acc2 = __builtin_elementwise_fma(a, wc2[kk / 2], acc2);
            acc2 = __builtin_elementwise_fma(b, wc2[kk / 2 + 1], acc2);
        }
        out[(size_t)node * HID + lane] = acc2.x + acc2.y;
    }
}

// ---------------------------------------------------------------------------
// Edge kernel: one wave per edge (chunked). lane = output column j (0..63).
// pe[j] = sum_k e[edge][k] * We[k][j] + be[j]
// score[j] = K[src][j]*Q[dst][j]/sqrt(8) + pe[j]  -> e_out
// a[head] = exp(clip(sum_d score, -5, 5)) -> atomicAdd z_sum[src][head]
// cnt[src] += 1
// ---------------------------------------------------------------------------
__global__ __launch_bounds__(64) void edge_kernel(
    const int* __restrict__ ei, const float* __restrict__ e,
    const float* __restrict__ We, const float* __restrict__ be,
    const float* __restrict__ Q, const float* __restrict__ K,
    float* __restrict__ e_out, float* __restrict__ z_sum,
    float* __restrict__ cnt, int n_edges, int epb)
{
    const int lane = threadIdx.x;

    // We column `lane`, packed as float2 along k (64 VGPRs)
    f32x2 w2[IN_EDGE / 2];
#pragma unroll
    for (int t = 0; t < IN_EDGE / 2; ++t) {
        w2[t].x = We[(2 * t) * HID + lane];
        w2[t].y = We[(2 * t + 1) * HID + lane];
    }
    const float bias = be[lane];

    int e0 = blockIdx.x * epb;
    int e1 = e0 + epb; if (e1 > n_edges) e1 = n_edges;
    for (int edge = e0; edge < e1; ++edge) {
        const float* __restrict__ erow = e + (size_t)edge * IN_EDGE;
        f32x2 acc2 = {0.0f, 0.0f};
#pragma unroll
        for (int kk = 0; kk < IN_EDGE; kk += 4) {
            float4 ev = *reinterpret_cast<const float4*>(erow + kk);
            f32x2 a = {ev.x, ev.y};
            f32x2 b = {ev.z, ev.w};
            acc2 = __builtin_elementwise_fma(a, w2[kk / 2], acc2);
            acc2 = __builtin_elementwise_fma(b, w2[kk / 2 + 1], acc2);
        }
        int src = ei[edge];
        int dst = ei[n_edges + edge];
        float kq = K[src * HID + lane] * Q[dst * HID + lane];
        float score = fmaf(kq, 0.35355339059327373f, acc2.x + acc2.y + bias);
        e_out[(size_t)edge * HID + lane] = score;

        // per-head sum over 8 consecutive lanes
        float s = score;
        s += __shfl_xor(s, 1);
        s += __shfl_xor(s, 2);
        s += __shfl_xor(s, 4);
        if ((lane & 7) == 0) {
            float a = expf(fminf(fmaxf(s, -5.0f), 5.0f));
            atomicAdd(&z_sum[src * HEADS + (lane >> 3)], a);
        }
        if (lane == 0) atomicAdd(&cnt[src], 1.0f);
    }
}

// ---------------------------------------------------------------------------
// Finalize: h_out[n,h,d] = V[n,h,d]*S / (S/max(cnt,1) + 1e-6)
// ---------------------------------------------------------------------------
__global__ __launch_bounds__(256) void finalize_kernel(
    const float* __restrict__ V, const float* __restrict__ z_sum,
    const float* __restrict__ cnt, float* __restrict__ h_out, int total)
{
    int i = blockIdx.x * 256 + threadIdx.x;
    if (i >= total) return;
    int node = i >> 6;
    int head = (i >> 3) & 7;
    float S = z_sum[node * HEADS + head];
    float c = fmaxf(cnt[node], 1.0f);
    h_out[i] = V[i] * S / (S / c + 1e-6f);
}

extern "C" void kernel_launch(void* const* d_in, const int* in_sizes, int n_in,
                              void* d_out, int out_size, void* d_ws, size_t ws_size,
                              hipStream_t stream)
{
    const int*   ei = (const int*)d_in[0];
    const float* h  = (const float*)d_in[1];
    const float* e  = (const float*)d_in[2];
    const float* WQ = (const float*)d_in[3];
    const float* bQ = (const float*)d_in[4];
    const float* WK = (const float*)d_in[5];
    const float* bK = (const float*)d_in[6];
    const float* WV = (const float*)d_in[7];
    const float* bV = (const float*)d_in[8];
    const float* We = (const float*)d_in[9];
    const float* be = (const float*)d_in[10];

    const int n_nodes = in_sizes[1] / IN_NODE;   // 50000
    const int n_edges = in_sizes[2] / IN_EDGE;   // 800000

    float* out_h = (float*)d_out;                       // n_nodes*64
    float* out_e = out_h + (size_t)n_nodes * HID;       // n_edges*64

    float* Q     = (float*)d_ws;
    float* K     = Q + (size_t)n_nodes * HID;
    float* V     = K + (size_t)n_nodes * HID;
    float* z_sum = V + (size_t)n_nodes * HID;
    float* cnt   = z_sum + (size_t)n_nodes * HEADS;

    // zero z_sum + cnt (contiguous: n_nodes*8 + n_nodes floats)
    hipMemsetAsync(z_sum, 0, (size_t)n_nodes * (HEADS + 1) * sizeof(float), stream);

    // QKV projection
    {
        const int chunks = 1536;
        const int npb = (n_nodes + chunks - 1) / chunks;
        dim3 grid(chunks, 3);
        qkv_kernel<<<grid, 64, 0, stream>>>(h, WQ, bQ, WK, bK, WV, bV,
                                            Q, K, V, n_nodes, npb);
    }
    // Edge kernel
    {
        const int nbe = 4096;
        const int epb = (n_edges + nbe - 1) / nbe;
        edge_kernel<<<nbe, 64, 0, stream>>>(ei, e, We, be, Q, K,
                                            out_e, z_sum, cnt, n_edges, epb);
    }
    // Finalize
    {
        const int total = n_nodes * HID;
        finalize_kernel<<<(total + 255) / 256, 256, 0, stream>>>(V, z_sum, cnt,
                                                                 out_h, total);
    }
}